// Round 1
// baseline (222.812 us; speedup 1.0000x reference)
//
#include <hip/hip_runtime.h>
#include <math.h>

// Problem constants
#define PUPIL 256
#define OUT_DIM 64
#define N_BINS 8
#define BATCH 16

__constant__ int PHASE_NS_C[N_BINS] = {1024, 988, 952, 918, 886, 856, 828, 802};

// ---------------------------------------------------------------------------
// Key math: reference crops fftshifted FFT at [N/2-32, N/2+32) in both axes.
// Shifted index j corresponds to frequency k = j - N/2 in [-32,31].
// padded input nonzero only on 256x256 pupil; the centered-pad offset
// contributes a unit-modulus prefactor e^{-2pi i k*pad/N} that |.|^2 kills.
// => PSF[u,v] = | sum_{y,x} P[y,x] W[y,ku] W[x,kv] |^2,
//    W[n,k] = e^{-2pi i (k-32) n / N},  P = obsc * exp(i * 2pi/lambda * opd).
// Two 256->64 complex contractions (stage1 over x, stage2 over y).
// ---------------------------------------------------------------------------

// Twiddle table: twid[bin][n][k] , n in [0,256), k index in [0,64) (freq k-32)
__global__ void twiddle_init(float2* __restrict__ twid) {
  int idx = blockIdx.x * 256 + threadIdx.x;       // 8*256*64 = 131072
  int kv  = idx & 63;
  int x   = (idx >> 6) & 255;
  int bin = idx >> 14;
  int N = PHASE_NS_C[bin];
  int k = kv - 32;
  int m = (k * x) % N;                            // exact integer reduction
  if (m < 0) m += N;
  float ang = -6.283185307179586f * (float)m / (float)N;
  float s, c;
  sincosf(ang, &s, &c);                           // precise; runs once, tiny
  twid[idx] = make_float2(c, s);
}

// Stage 1: G[b][bin][y][kv] = sum_x P[y][x] * W[x][kv]
// grid (4 ychunks, 8 bins, 16 batch), 256 threads, 4x4 register tile,
// K (=x) chunked by 32 -> 33 KB LDS -> 4 blocks/CU.
__global__ __launch_bounds__(256, 4) void stage1(
    const float* __restrict__ opd, const float* __restrict__ obsc,
    const float* __restrict__ lambdas, const float2* __restrict__ twid,
    float2* __restrict__ G)
{
  const int tid = threadIdx.x;
  const int ychunk = blockIdx.x, bin = blockIdx.y, b = blockIdx.z;
  const int ybase = ychunk * 64;
  const float w0 = 6.283185307179586f / lambdas[bin];

  __shared__ float Pre[32][65], Pim[32][65];   // [x_local][y_local], pad->2-way max
  __shared__ float Tre[32][64], Tim[32][64];   // [x_local][kv]

  const int ty  = tid >> 4;                    // 0..15 -> y group
  const int tkv = tid & 15;                    // 0..15 -> kv group (interleaved)

  float ar[4][4] = {{0}}, ai[4][4] = {{0}};

  for (int xc = 0; xc < 8; ++xc) {
    const int xbase = xc * 32;
    // --- load P tile (32 x  x 64 y): coalesced over x, compute phase
    {
      const int xl = tid & 31, yr0 = tid >> 5;   // 2048 elems / 256 thr = 8 it
      #pragma unroll
      for (int i = 0; i < 8; ++i) {
        int yl = yr0 + i * 8;
        int y = ybase + yl, x = xbase + xl;
        float o  = obsc[y * PUPIL + x];
        float od = opd[(b * PUPIL + y) * PUPIL + x];
        float s, c;
        __sincosf(w0 * od, &s, &c);
        Pre[xl][yl] = c * o;
        Pim[xl][yl] = s * o;
      }
    }
    // --- load T tile (32 x  x 64 kv): coalesced float2
    {
      const int kvl = tid & 63, xr0 = tid >> 6;
      #pragma unroll
      for (int i = 0; i < 8; ++i) {
        int xr = xr0 + i * 4;
        float2 w = twid[(bin * 256 + xbase + xr) * 64 + kvl];
        Tre[xr][kvl] = w.x;
        Tim[xr][kvl] = w.y;
      }
    }
    __syncthreads();
    // --- 4x4 complex MAC tile; T reads conflict-free (16 lanes consecutive),
    //     P reads are 16-lane broadcasts.
    for (int xl = 0; xl < 32; ++xl) {
      float tr[4], tiv[4], pr[4], piv[4];
      #pragma unroll
      for (int j = 0; j < 4; ++j) { tr[j] = Tre[xl][j * 16 + tkv]; tiv[j] = Tim[xl][j * 16 + tkv]; }
      #pragma unroll
      for (int i = 0; i < 4; ++i) { pr[i] = Pre[xl][ty * 4 + i]; piv[i] = Pim[xl][ty * 4 + i]; }
      #pragma unroll
      for (int i = 0; i < 4; ++i)
        #pragma unroll
        for (int j = 0; j < 4; ++j) {
          ar[i][j] += pr[i] * tr[j] - piv[i] * tiv[j];
          ai[i][j] += pr[i] * tiv[j] + piv[i] * tr[j];
        }
    }
    __syncthreads();
  }
  #pragma unroll
  for (int i = 0; i < 4; ++i)
    #pragma unroll
    for (int j = 0; j < 4; ++j) {
      int y  = ybase + ty * 4 + i;
      int kv = j * 16 + tkv;
      G[((b * N_BINS + bin) * 256 + y) * 64 + kv] = make_float2(ar[i][j], ai[i][j]);
    }
}

// Stage 2: H[ku][kv] = sum_y W[y][ku] * G[y][kv]; then |H|^2, block-wide sum,
// scale by sed/S, store. One block per (bin, b).
__global__ __launch_bounds__(256, 4) void stage2(
    const float2* __restrict__ G, const float2* __restrict__ twid,
    const float* __restrict__ sed, float* __restrict__ psf_s)
{
  const int tid = threadIdx.x;
  const int bin = blockIdx.x, b = blockIdx.y;

  __shared__ float Tre[32][64], Tim[32][64];   // [y_local][ku]
  __shared__ float Gre[32][64], Gim[32][64];   // [y_local][kv]
  __shared__ float red[4];

  const int tu  = tid >> 4;                    // ku group
  const int tkv = tid & 15;                    // kv group

  float ar[4][4] = {{0}}, ai[4][4] = {{0}};

  for (int yc = 0; yc < 8; ++yc) {
    const int ybase = yc * 32;
    {
      const int lc = tid & 63, r0 = tid >> 6;
      #pragma unroll
      for (int i = 0; i < 8; ++i) {
        int yr = r0 + i * 4;
        float2 w = twid[(bin * 256 + ybase + yr) * 64 + lc];
        Tre[yr][lc] = w.x;
        Tim[yr][lc] = w.y;
        float2 g = G[((b * N_BINS + bin) * 256 + ybase + yr) * 64 + lc];
        Gre[yr][lc] = g.x;
        Gim[yr][lc] = g.y;
      }
    }
    __syncthreads();
    for (int yl = 0; yl < 32; ++yl) {
      float tr[4], tiv[4], gr[4], gi[4];
      #pragma unroll
      for (int j = 0; j < 4; ++j) { gr[j] = Gre[yl][j * 16 + tkv]; gi[j] = Gim[yl][j * 16 + tkv]; }
      #pragma unroll
      for (int i = 0; i < 4; ++i) { tr[i] = Tre[yl][tu * 4 + i]; tiv[i] = Tim[yl][tu * 4 + i]; }
      #pragma unroll
      for (int i = 0; i < 4; ++i)
        #pragma unroll
        for (int j = 0; j < 4; ++j) {
          ar[i][j] += tr[i] * gr[j] - tiv[i] * gi[j];
          ai[i][j] += tr[i] * gi[j] + tiv[i] * gr[j];
        }
    }
    __syncthreads();
  }

  // |H|^2 + block reduction of the 64x64 sum
  float pv[4][4];
  float lsum = 0.f;
  #pragma unroll
  for (int i = 0; i < 4; ++i)
    #pragma unroll
    for (int j = 0; j < 4; ++j) {
      pv[i][j] = ar[i][j] * ar[i][j] + ai[i][j] * ai[i][j];
      lsum += pv[i][j];
    }
  #pragma unroll
  for (int off = 32; off > 0; off >>= 1) lsum += __shfl_down(lsum, off);
  const int lane = tid & 63, wid = tid >> 6;
  if (lane == 0) red[wid] = lsum;
  __syncthreads();
  const float S = red[0] + red[1] + red[2] + red[3];
  const float scale = sed[bin] / S;

  #pragma unroll
  for (int i = 0; i < 4; ++i)
    #pragma unroll
    for (int j = 0; j < 4; ++j) {
      int u = tu * 4 + i, v = j * 16 + tkv;
      psf_s[(size_t)(b * N_BINS + bin) * 4096 + u * 64 + v] = pv[i][j] * scale;
    }
}

// Sum the 8 pre-scaled bins into the output.
__global__ void combine(const float* __restrict__ psf_s, float* __restrict__ out) {
  int idx = blockIdx.x * 256 + threadIdx.x;    // 16*64*64 = 65536
  int b = idx >> 12, p = idx & 4095;
  float acc = 0.f;
  #pragma unroll
  for (int bin = 0; bin < N_BINS; ++bin)
    acc += psf_s[(size_t)(b * N_BINS + bin) * 4096 + p];
  out[idx] = acc;
}

extern "C" void kernel_launch(void* const* d_in, const int* in_sizes, int n_in,
                              void* d_out, int out_size, void* d_ws, size_t ws_size,
                              hipStream_t stream) {
  const float* opd     = (const float*)d_in[0];   // 16*256*256
  const float* obsc    = (const float*)d_in[1];   // 256*256
  const float* lambdas = (const float*)d_in[2];   // 8
  const float* sed     = (const float*)d_in[3];   // 8
  float* out = (float*)d_out;                     // 16*64*64

  // workspace: twid (1 MB) | G (16 MB) | psf_s (2 MB)  => ~19.9 MB total
  float2* twid  = (float2*)d_ws;
  float2* G     = twid + (size_t)N_BINS * 256 * 64;
  float*  psf_s = (float*)(G + (size_t)BATCH * N_BINS * 256 * 64);

  twiddle_init<<<512, 256, 0, stream>>>(twid);
  stage1<<<dim3(4, N_BINS, BATCH), 256, 0, stream>>>(opd, obsc, lambdas, twid, G);
  stage2<<<dim3(N_BINS, BATCH), 256, 0, stream>>>(G, twid, sed, psf_s);
  combine<<<256, 256, 0, stream>>>(psf_s, out);
}